// Round 3
// baseline (4076.771 us; speedup 1.0000x reference)
//
#include <hip/hip_runtime.h>
#include <cmath>
#include <climits>

#define N_ 2048
#define T_ 4096
#define MAXSP 256
#define CHUNK 256
#define NCHUNK (T_ / CHUNK)   // 16

// ---------------- workspace layout (d_ws) ----------------
#define WS_EIDX_OFF   0
#define WS_CNT_OFF    (T_ * 4)
#define WS_SNAP_OFF   (T_ * 4 + NCHUNK * 4)

typedef float f2 __attribute__((ext_vector_type(2)));

__device__ __forceinline__ int imin(int a, int b) { return a < b ? a : b; }

// Raw workgroup barrier with LDS visibility only (no vmcnt drain):
// global prefetches (ic, u_re, w-row) stay in flight across it.
__device__ __forceinline__ void lds_barrier() {
    asm volatile("s_waitcnt lgkmcnt(0)\n\ts_barrier" ::: "memory");
}

// Fill tevents/yevents with +inf, event_types with 0.
__global__ void snn_init_tail(float* __restrict__ out) {
    const size_t base    = (size_t)T_ * N_ * 3;
    const size_t inf_cnt = (size_t)MAXSP + (size_t)MAXSP * N_ * 3;
    const size_t tot     = inf_cnt + (size_t)MAXSP * N_;
    size_t idx = (size_t)blockIdx.x * blockDim.x + threadIdx.x;
    if (idx < tot) {
        out[base + idx] = (idx < inf_cnt) ? __builtin_inff() : 0.0f;
    }
}

// ---------------- Kernel A: sequential scan (1 WG, reduction-ahead) ------
// Invariant at top of iter k:
//   vA,sA      = post-transition state after step k-1 (eidx-FREE: mask
//                implies event, so per-lane selects never need the global
//                reduction result)
//   iRaw       = decayed i after step k-1 WITHOUT the event w row
//   w2         = w row of event k-1 (or exact 0.0 if none) -> i finalize
//   m0c,m1c,s1c,bAny = per-lane mask/intensity for step k (iter k-1's [E])
//   red[k&3]   = fully-reduced event index for step k (drained by the
//                barrier of iter k-1) -> readable at the TOP of iter k.
// Serial chain per iter (Chain Y) is pure per-lane VALU:
//   ip add -> Euler -> selects -> softplus -> ballot -> atomicMin -> barrier
// The eidx read / readfirstlane / w-row load (Chain X) hangs OFF that chain
// and has ~a full iteration of latency slack.
extern "C" __global__ void __launch_bounds__(1024)
snn_scan(const float* __restrict__ w,   const float* __restrict__ mu,
         const float* __restrict__ v0,  const float* __restrict__ i0,
         const float* __restrict__ ic,  const float* __restrict__ u_init,
         const float* __restrict__ u_re, float* __restrict__ out,
         int* __restrict__ ws_eidx, int* __restrict__ ws_cnt,
         float* __restrict__ ws_snap)
{
#pragma clang fp contract(off)
    const int tid = threadIdx.x;
    const int n0  = tid * 2;             // two adjacent neurons -> f2 ops
    const int wv  = tid >> 6, lane = tid & 63;
    const float dt = 1.0f / 4096.0f;     // exact: 2^-12
    const float mu1 = mu[0], mu2 = mu[1];

    float* tev = out + (size_t)T_ * N_ * 3;
    float* nsp = tev + MAXSP + (size_t)MAXSP * N_ * 3 + (size_t)MAXSP * N_;

    f2 vA, sA, iRaw;
    vA   = *(const f2*)(v0 + n0);
    iRaw = *(const f2*)(i0 + n0);
    { f2 a = *(const f2*)(u_init + n0);
      sA.x = logf(a.x) - 0.01f; sA.y = logf(a.y) - 0.01f; }  // one-time precise

    f2 w2; w2.x = 0.0f; w2.y = 0.0f;

    // Slot lifecycle (mod 4): atomics at iter s-1 (pre-barrier) -> read at
    // top of iter s -> reset by tid0 at iter s+1 (post-barrier) -> next
    // atomics at iter s+3.  Every conflicting pair is separated by >=1
    // lds_barrier (lgkmcnt(0) drain + s_barrier).
    __shared__ int red[4];
    if (tid == 0) { red[0] = INT_MAX; red[1] = INT_MAX;
                    red[2] = INT_MAX; red[3] = INT_MAX; }

    // 3-deep prefetch pipeline for ic and u_re
    const float* icp = ic + n0;
    const float* up  = u_re + n0;
    f2 icA = *(const f2*)(icp);
    f2 icB = *(const f2*)(icp + N_);
    f2 icC = *(const f2*)(icp + 2 * N_);
    f2 uA  = *(const f2*)(up);
    f2 uB  = *(const f2*)(up + N_);
    f2 uC  = *(const f2*)(up + 2 * N_);
    icp += 3 * N_; up += 3 * N_;

    lds_barrier();   // red[] init visible before prologue atomics

    // ---- prologue: mask/candidate for step 0 -> slot 0
    f2 s1c; bool m0c, m1c, bAny;
    {
        f2 sp;
        bool slow = (fminf(vA.x, vA.y) < 16.0f);
        if (__ballot(slow)) {
            sp.x = fmaxf(vA.x, 0.0f) + __logf(1.0f + __expf(-fabsf(vA.x)));
            sp.y = fmaxf(vA.y, 0.0f) + __logf(1.0f + __expf(-fabsf(vA.y)));
        } else {
            sp = vA;
        }
        s1c = sA + dt * sp;
        m0c = (s1c.x >= 0.0f); m1c = (s1c.y >= 0.0f);
        unsigned long long b0 = __ballot(m0c);
        unsigned long long b1 = __ballot(m1c);
        bAny = ((b0 | b1) != 0ull);
        if (bAny) {
            int c0 = b0 ? (((int)__ffsll((long long)b0) - 1) << 1) : INT_MAX;
            int c1 = b1 ? ((((int)__ffsll((long long)b1) - 1) << 1) | 1) : INT_MAX;
            int cand = (wv << 7) + imin(c0, c1);
            if (lane == 0) atomicMin(&red[0], cand);
        }
    }
    lds_barrier();   // drain step-0 candidate atomics

    int cnt = 0;
#pragma unroll 4
    for (int k = 0; k < T_; ++k) {
        // [X1] issue the slot read early; nothing on Chain Y consumes it.
        int eidxRaw = red[k & 3];

        // [A] finalize i_{k-1}: w2 is the event-(k-1) row or exact 0.0
        //     (i > 0 always, so +0.0 is bit-exact vs the guarded add).
        f2 ip = iRaw + w2;

        // [B] chunk snapshot: state after step k-1 (= chunk-start state)
        if ((k & (CHUNK - 1)) == 0) {
            const int c = k >> 8;
            float* spn = ws_snap + (size_t)c * 3 * N_;
            *(f2*)(spn + n0)          = vA;
            *(f2*)(spn + N_ + n0)     = ip;
            *(f2*)(spn + 2 * N_ + n0) = sA;
            if (tid == 0) ws_cnt[c] = cnt;
        }

        // [C] Euler for step k — reference op order, no FMA contraction
        f2 v1 = vA + dt * (mu1 * ((ip + icA) - vA));
        iRaw  = ip + dt * ((-mu2) * ip);

        // [D] per-lane transitions for step k — eidx-FREE.
        //     mask implies event, so the selects match the reference in
        //     every case; bAny (this wave's ballot from iter k-1) lets
        //     no-spike waves skip the logs entirely.
        vA.x = m0c ? (v1.x - 1.0f) : v1.x;
        vA.y = m1c ? (v1.y - 1.0f) : v1.y;
        if (bAny) {
            sA.x = m0c ? (__logf(uA.x) - 0.01f) : s1c.x;
            sA.y = m1c ? (__logf(uA.y) - 0.01f) : s1c.y;
        } else {
            sA = s1c;
        }

        // [X2] consume the slot read: scalarize, issue w-row load (consumed
        //      at [A] of iter k+1 -> ~full body of slack), bookkeeping.
        int eidx = __builtin_amdgcn_readfirstlane(eidxRaw);
        const bool evK = (eidx != INT_MAX);
        w2.x = 0.0f; w2.y = 0.0f;
        if (evK) {
            w2 = *(const f2*)(w + (size_t)eidx * N_ + n0);
            if (tid == 0) {
                ws_eidx[k] = eidx;
                if (cnt < MAXSP) tev[cnt] = (float)(k + 1) * dt;
            }
            if (cnt < MAXSP) cnt++;
        } else if (tid == 0) {
            ws_eidx[k] = -1;
        }

        // [E] mask/candidate for step k+1 from post-step-k state (purely
        //     per-lane: the event-k w row only reaches masks at step k+2).
        if (k + 1 < T_) {
            f2 sp;
            bool slow = (fminf(vA.x, vA.y) < 16.0f);
            if (__ballot(slow)) {
                sp.x = fmaxf(vA.x, 0.0f) + __logf(1.0f + __expf(-fabsf(vA.x)));
                sp.y = fmaxf(vA.y, 0.0f) + __logf(1.0f + __expf(-fabsf(vA.y)));
            } else {
                sp = vA;
            }
            s1c = sA + dt * sp;
            m0c = (s1c.x >= 0.0f); m1c = (s1c.y >= 0.0f);
            unsigned long long b0 = __ballot(m0c);
            unsigned long long b1 = __ballot(m1c);
            bAny = ((b0 | b1) != 0ull);
            if (bAny) {
                int c0 = b0 ? (((int)__ffsll((long long)b0) - 1) << 1) : INT_MAX;
                int c1 = b1 ? ((((int)__ffsll((long long)b1) - 1) << 1) | 1) : INT_MAX;
                int cand = (wv << 7) + imin(c0, c1);
                if (lane == 0) atomicMin(&red[(k + 1) & 3], cand);
            }
        }

        // [F] barrier drains the slot-(k+1) atomics; slot (k+1) becomes
        //     readable at the top of iter k+1.
        lds_barrier();
        if (tid == 0) red[(k + 3) & 3] = INT_MAX;   // deferred, race-free reset

        // [G] advance 3-deep prefetch
        icA = icB; icB = icC; uA = uB; uB = uC;
        if (k + 3 < T_) {
            icC = *(const f2*)icp;
            uC  = *(const f2*)up;
            icp += N_; up += N_;
        }
    }

    if (tid == 0) nsp[0] = (float)cnt;
}

// ---------------- Kernel B: parallel replay ----------------
extern "C" __global__ void __launch_bounds__(256)
snn_replay(const float* __restrict__ w,   const float* __restrict__ mu,
           const float* __restrict__ ic,  const float* __restrict__ u_re,
           float* __restrict__ out,
           const int* __restrict__ ws_eidx, const int* __restrict__ ws_cnt,
           const float* __restrict__ ws_snap)
{
#pragma clang fp contract(off)
    const int c = blockIdx.x >> 3;                       // chunk
    const int n = ((blockIdx.x & 7) << 8) + threadIdx.x; // neuron
    const float dt = 1.0f / 4096.0f;
    const float mu1 = mu[0], mu2 = mu[1];

    float* ys  = out;
    float* yev = out + (size_t)T_ * N_ * 3 + MAXSP;
    float* et  = yev + (size_t)MAXSP * N_ * 3;

    const float* sp = ws_snap + (size_t)c * 3 * N_;
    float v  = sp[n];
    float ii = sp[N_ + n];
    float ss = sp[2 * N_ + n];
    int cnt = ws_cnt[c];

    const int t0 = c << 8;
    const float* icp = ic + (size_t)t0 * N_ + n;
    const float* up  = u_re + (size_t)t0 * N_ + n;
    float* yr = ys + ((size_t)t0 * N_ + n) * 3;

    for (int k = 0; k < CHUNK; ++k) {
        const int t = t0 + k;
        const int e = ws_eidx[t];          // uniform scalar load
        const float icv = icp[0];

        float v1 = v + dt * (mu1 * ((ii + icv) - v));
        float i1 = ii + dt * ((-mu2) * ii);
        // same bit-exact fast/slow softplus as the scan
        float spv;
        if (__ballot(v < 16.0f)) {
            spv = fmaxf(v, 0.0f) + __logf(1.0f + __expf(-fabsf(v)));
        } else {
            spv = v;
        }
        float s1 = ss + dt * spv;
        bool m = (s1 >= 0.0f);

        if (e >= 0) {                      // event step (uniform branch)
            float wv_ = w[(size_t)e * N_ + n];
            float uu  = up[0];
            if (cnt < MAXSP) {             // record pre-transition state
                float* ye = yev + ((size_t)cnt * N_ + n) * 3;
                ye[0] = v1; ye[1] = i1; ye[2] = s1;
                et[(size_t)cnt * N_ + n] = m ? 1.0f : 0.0f;
                cnt++;
            }
            v  = m ? (v1 - 1.0f) : v1;
            ii = i1 + wv_;
            ss = m ? (__logf(uu) - 0.01f) : s1;
        } else {
            v = v1; ii = i1; ss = s1;
        }

        yr[0] = v; yr[1] = ii; yr[2] = ss;

        icp += N_; up += N_; yr += (size_t)3 * N_;
    }
}

extern "C" void kernel_launch(void* const* d_in, const int* in_sizes, int n_in,
                              void* d_out, int out_size, void* d_ws, size_t ws_size,
                              hipStream_t stream) {
    const float* w      = (const float*)d_in[0];
    const float* mu     = (const float*)d_in[1];
    const float* v0     = (const float*)d_in[2];
    const float* i0     = (const float*)d_in[3];
    const float* ic     = (const float*)d_in[4];
    const float* u_init = (const float*)d_in[5];
    const float* u_re   = (const float*)d_in[6];
    float* out = (float*)d_out;

    char* ws = (char*)d_ws;
    int*   ws_eidx = (int*)(ws + WS_EIDX_OFF);
    int*   ws_cnt  = (int*)(ws + WS_CNT_OFF);
    float* ws_snap = (float*)(ws + WS_SNAP_OFF);

    const size_t tail = (size_t)MAXSP + (size_t)MAXSP * N_ * 3 + (size_t)MAXSP * N_;
    int blocks = (int)((tail + 255) / 256);
    snn_init_tail<<<blocks, 256, 0, stream>>>(out);

    snn_scan<<<1, 1024, 0, stream>>>(w, mu, v0, i0, ic, u_init, u_re,
                                     out, ws_eidx, ws_cnt, ws_snap);

    snn_replay<<<NCHUNK * 8, 256, 0, stream>>>(w, mu, ic, u_re, out,
                                               ws_eidx, ws_cnt, ws_snap);
}

// Round 4
// 3355.697 us; speedup vs baseline: 1.2149x; 1.2149x over previous
//
#include <hip/hip_runtime.h>
#include <cmath>
#include <climits>

#define N_ 2048
#define T_ 4096
#define MAXSP 256
#define CHUNK 256
#define NCHUNK (T_ / CHUNK)   // 16

// ---------------- workspace layout (d_ws) ----------------
#define WS_EIDX_OFF   0
#define WS_CNT_OFF    (T_ * 4)
#define WS_SNAP_OFF   (T_ * 4 + NCHUNK * 4)

typedef float f4 __attribute__((ext_vector_type(4)));

__device__ __forceinline__ int imin(int a, int b) { return a < b ? a : b; }

// Raw workgroup barrier with LDS visibility only (no vmcnt drain):
// global prefetches (ic, u_re, w-row) stay in flight across it.
__device__ __forceinline__ void lds_barrier() {
    asm volatile("s_waitcnt lgkmcnt(0)\n\ts_barrier" ::: "memory");
}

// Fill tevents/yevents with +inf, event_types with 0.
__global__ void snn_init_tail(float* __restrict__ out) {
    const size_t base    = (size_t)T_ * N_ * 3;
    const size_t inf_cnt = (size_t)MAXSP + (size_t)MAXSP * N_ * 3;
    const size_t tot     = inf_cnt + (size_t)MAXSP * N_;
    size_t idx = (size_t)blockIdx.x * blockDim.x + threadIdx.x;
    if (idx < tot) {
        out[base + idx] = (idx < inf_cnt) ? __builtin_inff() : 0.0f;
    }
}

// ---------------- Kernel A: sequential scan (1 WG) ----------------------
// EXACT R1 structure (best measured: 2824 us) with ONE variable changed:
// 512 threads x 4 neurons (f4) instead of 1024 x 2 (f2).
//   - 8 waves instead of 16: half the barrier participants, half the
//     lane-0 LDS atomics, 2 waves/SIMD instead of 4.
//   - dwordx4 loads/stores for ic/u/w/snapshot: half the memory instrs.
// All arithmetic per neuron is bit-identical (same ops, same order).
extern "C" __global__ void __launch_bounds__(512)
snn_scan(const float* __restrict__ w,   const float* __restrict__ mu,
         const float* __restrict__ v0,  const float* __restrict__ i0,
         const float* __restrict__ ic,  const float* __restrict__ u_init,
         const float* __restrict__ u_re, float* __restrict__ out,
         int* __restrict__ ws_eidx, int* __restrict__ ws_cnt,
         float* __restrict__ ws_snap)
{
#pragma clang fp contract(off)
    const int tid = threadIdx.x;
    const int n0  = tid * 4;             // four adjacent neurons -> f4 ops
    const int wv  = tid >> 6, lane = tid & 63;
    const float dt = 1.0f / 4096.0f;     // exact: 2^-12
    const float mu1 = mu[0], mu2 = mu[1];

    float* tev = out + (size_t)T_ * N_ * 3;
    float* nsp = tev + MAXSP + (size_t)MAXSP * N_ * 3 + (size_t)MAXSP * N_;

    // pipeline state: (vc,sc) = post-transition state of step k-1;
    // i1p = pre-w i1 of step k-1; (evp,w2) = pending event / w-row load.
    f4 vc, sc, i1p;
    vc  = *(const f4*)(v0 + n0);
    i1p = *(const f4*)(i0 + n0);
    { f4 a = *(const f4*)(u_init + n0);
      sc.x = logf(a.x) - 0.01f; sc.y = logf(a.y) - 0.01f;
      sc.z = logf(a.z) - 0.01f; sc.w = logf(a.w) - 0.01f; }  // one-time precise

    bool evp = false;
    f4 w2; w2.x = 0.0f; w2.y = 0.0f; w2.z = 0.0f; w2.w = 0.0f;

    // Slot lifecycle (mod 4): atomics at iter s (pre-barrier) -> read at
    // iter s (post-barrier) -> reset by tid0 at iter s (right after read,
    // targeting slot s+2) -> next atomics at iter s+2 (>=1 barrier apart).
    __shared__ int red[4];
    if (tid == 0) { red[0] = INT_MAX; red[1] = INT_MAX;
                    red[2] = INT_MAX; red[3] = INT_MAX; }

    // 2-deep prefetch pipeline for ic and u_re
    const float* icp = ic + n0;
    const float* up  = u_re + n0;
    f4 icA = *(const f4*)(icp);
    f4 icB = *(const f4*)(icp + N_);
    f4 uA  = *(const f4*)(up);
    f4 uB  = *(const f4*)(up + N_);
    icp += 2 * N_; up += 2 * N_;

    lds_barrier();   // red[] init visible before first atomics

    int cnt = 0;
#pragma unroll 4
    for (int k = 0; k < T_; ++k) {
        // [1] softplus + mask_k from (vc, sc) — independent of pending w-row.
        // Fast path: for v >= 16, fmax(v,0)+__logf(1+__expf(-v)) rounds to
        // EXACTLY v in fp32, so both paths are bit-identical; take the
        // transcendental path only if any lane in the wave has v < 16.
        f4 sp;
        float vmin = fminf(fminf(vc.x, vc.y), fminf(vc.z, vc.w));
        bool slow = (vmin < 16.0f);
        if (__ballot(slow)) {
            sp.x = fmaxf(vc.x, 0.0f) + __logf(1.0f + __expf(-fabsf(vc.x)));
            sp.y = fmaxf(vc.y, 0.0f) + __logf(1.0f + __expf(-fabsf(vc.y)));
            sp.z = fmaxf(vc.z, 0.0f) + __logf(1.0f + __expf(-fabsf(vc.z)));
            sp.w = fmaxf(vc.w, 0.0f) + __logf(1.0f + __expf(-fabsf(vc.w)));
        } else {
            sp = vc;
        }
        f4 s1 = sc + dt * sp;
        bool m0 = (s1.x >= 0.0f), m1 = (s1.y >= 0.0f);
        bool m2 = (s1.z >= 0.0f), m3 = (s1.w >= 0.0f);

        // wave candidate, fully scalar: neuron of (lane, sub j) within the
        // wave is (lane<<2)|j, so the wave minimum is
        // (wv<<8) + min_j(((ctz(bj))<<2)|j).  One atomicMin per wave.
        unsigned long long b0 = __ballot(m0);
        unsigned long long b1 = __ballot(m1);
        unsigned long long b2 = __ballot(m2);
        unsigned long long b3 = __ballot(m3);
        if (b0 | b1 | b2 | b3) {
            int c0 = b0 ? (((int)__ffsll((long long)b0) - 1) << 2)       : INT_MAX;
            int c1 = b1 ? ((((int)__ffsll((long long)b1) - 1) << 2) | 1) : INT_MAX;
            int c2 = b2 ? ((((int)__ffsll((long long)b2) - 1) << 2) | 2) : INT_MAX;
            int c3 = b3 ? ((((int)__ffsll((long long)b3) - 1) << 2) | 3) : INT_MAX;
            int cand = (wv << 8) + imin(imin(c0, c1), imin(c2, c3));
            if (lane == 0) atomicMin(&red[k & 3], cand);
        }

        // [2] barrier (drains this slot's atomics) + broadcast read
        lds_barrier();
        int eidx = red[k & 3];
        eidx = __builtin_amdgcn_readfirstlane(eidx);   // scalarize
        if (tid == 0) red[(k + 2) & 3] = INT_MAX;      // deferred reset

        // [3] finalize i_{k-1}: waits the pending w[k-1] row load
        f4 ip = i1p;
        if (evp) ip += w2;

        // chunk snapshot: state after step k-1 (= chunk-start state)
        if ((k & (CHUNK - 1)) == 0) {
            const int c = k >> 8;
            float* spn = ws_snap + (size_t)c * 3 * N_;
            *(f4*)(spn + n0)          = vc;
            *(f4*)(spn + N_ + n0)     = ip;
            *(f4*)(spn + 2 * N_ + n0) = sc;
            if (tid == 0) ws_cnt[c] = cnt;
        }

        // [4] Euler for step k — reference op order, no FMA contraction
        f4 v1 = vc + dt * (mu1 * ((ip + icA) - vc));
        i1p   = ip + dt * ((-mu2) * ip);

        // [5]+[6] event handling + per-lane transitions
        evp = (eidx != INT_MAX);
        vc.x = m0 ? (v1.x - 1.0f) : v1.x;
        vc.y = m1 ? (v1.y - 1.0f) : v1.y;
        vc.z = m2 ? (v1.z - 1.0f) : v1.z;
        vc.w = m3 ? (v1.w - 1.0f) : v1.w;
        if (evp) {
            // issue next pending w-row load (waited next iteration at [3])
            w2 = *(const f4*)(w + (size_t)eidx * N_ + n0);
            sc.x = m0 ? (__logf(uA.x) - 0.01f) : s1.x;
            sc.y = m1 ? (__logf(uA.y) - 0.01f) : s1.y;
            sc.z = m2 ? (__logf(uA.z) - 0.01f) : s1.z;
            sc.w = m3 ? (__logf(uA.w) - 0.01f) : s1.w;
            if (tid == 0) {
                ws_eidx[k] = eidx;
                if (cnt < MAXSP) tev[cnt] = (float)(k + 1) * dt;
            }
            if (cnt < MAXSP) cnt++;
        } else {
            sc = s1;
            if (tid == 0) ws_eidx[k] = -1;
        }

        // [7] advance 2-deep prefetch
        icA = icB; uA = uB;
        if (k + 2 < T_) {
            icB = *(const f4*)icp;
            uB  = *(const f4*)up;
            icp += N_; up += N_;
        }
    }

    if (tid == 0) nsp[0] = (float)cnt;
}

// ---------------- Kernel B: parallel replay ----------------
extern "C" __global__ void __launch_bounds__(256)
snn_replay(const float* __restrict__ w,   const float* __restrict__ mu,
           const float* __restrict__ ic,  const float* __restrict__ u_re,
           float* __restrict__ out,
           const int* __restrict__ ws_eidx, const int* __restrict__ ws_cnt,
           const float* __restrict__ ws_snap)
{
#pragma clang fp contract(off)
    const int c = blockIdx.x >> 3;                       // chunk
    const int n = ((blockIdx.x & 7) << 8) + threadIdx.x; // neuron
    const float dt = 1.0f / 4096.0f;
    const float mu1 = mu[0], mu2 = mu[1];

    float* ys  = out;
    float* yev = out + (size_t)T_ * N_ * 3 + MAXSP;
    float* et  = yev + (size_t)MAXSP * N_ * 3;

    const float* sp = ws_snap + (size_t)c * 3 * N_;
    float v  = sp[n];
    float ii = sp[N_ + n];
    float ss = sp[2 * N_ + n];
    int cnt = ws_cnt[c];

    const int t0 = c << 8;
    const float* icp = ic + (size_t)t0 * N_ + n;
    const float* up  = u_re + (size_t)t0 * N_ + n;
    float* yr = ys + ((size_t)t0 * N_ + n) * 3;

    for (int k = 0; k < CHUNK; ++k) {
        const int t = t0 + k;
        const int e = ws_eidx[t];          // uniform scalar load
        const float icv = icp[0];

        float v1 = v + dt * (mu1 * ((ii + icv) - v));
        float i1 = ii + dt * ((-mu2) * ii);
        // same bit-exact fast/slow softplus as the scan
        float spv;
        if (__ballot(v < 16.0f)) {
            spv = fmaxf(v, 0.0f) + __logf(1.0f + __expf(-fabsf(v)));
        } else {
            spv = v;
        }
        float s1 = ss + dt * spv;
        bool m = (s1 >= 0.0f);

        if (e >= 0) {                      // event step (uniform branch)
            float wv_ = w[(size_t)e * N_ + n];
            float uu  = up[0];
            if (cnt < MAXSP) {             // record pre-transition state
                float* ye = yev + ((size_t)cnt * N_ + n) * 3;
                ye[0] = v1; ye[1] = i1; ye[2] = s1;
                et[(size_t)cnt * N_ + n] = m ? 1.0f : 0.0f;
                cnt++;
            }
            v  = m ? (v1 - 1.0f) : v1;
            ii = i1 + wv_;
            ss = m ? (__logf(uu) - 0.01f) : s1;
        } else {
            v = v1; ii = i1; ss = s1;
        }

        yr[0] = v; yr[1] = ii; yr[2] = ss;

        icp += N_; up += N_; yr += (size_t)3 * N_;
    }
}

extern "C" void kernel_launch(void* const* d_in, const int* in_sizes, int n_in,
                              void* d_out, int out_size, void* d_ws, size_t ws_size,
                              hipStream_t stream) {
    const float* w      = (const float*)d_in[0];
    const float* mu     = (const float*)d_in[1];
    const float* v0     = (const float*)d_in[2];
    const float* i0     = (const float*)d_in[3];
    const float* ic     = (const float*)d_in[4];
    const float* u_init = (const float*)d_in[5];
    const float* u_re   = (const float*)d_in[6];
    float* out = (float*)d_out;

    char* ws = (char*)d_ws;
    int*   ws_eidx = (int*)(ws + WS_EIDX_OFF);
    int*   ws_cnt  = (int*)(ws + WS_CNT_OFF);
    float* ws_snap = (float*)(ws + WS_SNAP_OFF);

    const size_t tail = (size_t)MAXSP + (size_t)MAXSP * N_ * 3 + (size_t)MAXSP * N_;
    int blocks = (int)((tail + 255) / 256);
    snn_init_tail<<<blocks, 256, 0, stream>>>(out);

    snn_scan<<<1, 512, 0, stream>>>(w, mu, v0, i0, ic, u_init, u_re,
                                    out, ws_eidx, ws_cnt, ws_snap);

    snn_replay<<<NCHUNK * 8, 256, 0, stream>>>(w, mu, ic, u_re, out,
                                               ws_eidx, ws_cnt, ws_snap);
}